// Round 8
// baseline (411.960 us; speedup 1.0000x reference)
//
#include <hip/hip_runtime.h>
#include <math.h>

#define C 128

typedef unsigned short u16;
typedef __attribute__((ext_vector_type(8))) short short8;
typedef __attribute__((ext_vector_type(4))) float f32x4;
typedef __attribute__((ext_vector_type(4))) u16 u16x4;
typedef __attribute__((ext_vector_type(2))) u16 u16x2;

__device__ __forceinline__ float b2f(u16 u) {
    union { unsigned i; float f; } x; x.i = (unsigned)u << 16; return x.f;
}
__device__ __forceinline__ u16 f2b(float f) {
    union { float f; unsigned i; } x; x.f = f;
    unsigned r = x.i + 0x7FFFu + ((x.i >> 16) & 1u);
    return (u16)(r >> 16);
}
__device__ __forceinline__ float lrelu(float x) { return x > 0.f ? x : 0.2f * x; }

// ---------------- CSR build (edge_index arrives int32) ----------------

__global__ void hist_kernel(const int* __restrict__ ei, int E, int N,
                            int* __restrict__ count) {
    int total = E + N;
    for (int e = blockIdx.x * blockDim.x + threadIdx.x; e < total;
         e += gridDim.x * blockDim.x) {
        int d = (e < E) ? ei[E + e] : (e - E);
        if ((unsigned)d < (unsigned)N) atomicAdd(&count[d], 1);
    }
}

__global__ __launch_bounds__(1024) void scan_kernel(const int* __restrict__ count,
                                                    int* __restrict__ offs,
                                                    int* __restrict__ cursor, int N) {
    int tid = threadIdx.x, lane = tid & 63, wid = tid >> 6;   // 16 waves
    int CH = (N + 1023) >> 10;
    int base = tid * CH;
    int s = 0;
    for (int j = 0; j < CH; ++j) {
        int i = base + j;
        if (i < N) s += count[i];
    }
    int own = s;
    #pragma unroll
    for (int d = 1; d < 64; d <<= 1) {
        int v = __shfl_up(s, d);
        if (lane >= d) s += v;
    }
    __shared__ int wtot[16];
    if (lane == 63) wtot[wid] = s;
    __syncthreads();
    if (tid < 16) {
        int t = wtot[tid];
        int u = t;
        #pragma unroll
        for (int d = 1; d < 16; d <<= 1) {
            int v = __shfl_up(u, d);
            if (tid >= d) u += v;
        }
        wtot[tid] = u - t;            // exclusive wave offset
        if (tid == 15) offs[N] = u;   // grand total
    }
    __syncthreads();
    int run = wtot[wid] + s - own;    // exclusive prefix for this thread
    for (int j = 0; j < CH; ++j) {
        int i = base + j;
        if (i < N) {
            offs[i] = run;
            cursor[i] = run;
            run += count[i];
        }
    }
}

__global__ void scatter_kernel(const int* __restrict__ ei, int E, int N,
                               int* __restrict__ cursor, int* __restrict__ srcs,
                               int* __restrict__ dsts) {
    int total = E + N;
    for (int e = blockIdx.x * blockDim.x + threadIdx.x; e < total;
         e += gridDim.x * blockDim.x) {
        int sNode, d;
        if (e < E) { sNode = ei[e]; d = ei[E + e]; }
        else       { sNode = e - E; d = sNode; }
        if ((unsigned)d < (unsigned)N && (unsigned)sNode < (unsigned)N) {
            int pos = atomicAdd(&cursor[d], 1);
            srcs[pos] = sNode;
            dsts[pos] = d;
        }
    }
}

// Wc[l][o][h*128+i] = 0.25 * Wl[h][i][o]  (head-mean folded; [128 cols][512 k] bf16)
__global__ __launch_bounds__(128) void cvt_w_kernel(const float* __restrict__ W1,
                                                    const float* __restrict__ Wr,
                                                    const float* __restrict__ W2,
                                                    u16* __restrict__ Wc) {
    int b = blockIdx.x;            // 0..383
    int l = b >> 7, o = b & 127;
    const float* W = (l == 0) ? W1 : (l == 1) ? Wr : W2;
    int i = threadIdx.x;
    u16* dst = Wc + ((size_t)l * C + o) * 512;
    #pragma unroll
    for (int h = 0; h < 4; ++h) {
        dst[h * C + i] = f2b(0.25f * W[((size_t)h * C + i) * C + o]);
    }
}

// ---------------- W@a vectors: vs/vd[slot][i], 12 slots (W1:0-3, Wr:4-7, W2:8-11) ----

__global__ __launch_bounds__(256) void wvec_kernel(const float* __restrict__ W1,
                                                   const float* __restrict__ as1,
                                                   const float* __restrict__ ad1,
                                                   const float* __restrict__ Wr,
                                                   const float* __restrict__ asr,
                                                   const float* __restrict__ adr,
                                                   const float* __restrict__ W2,
                                                   const float* __restrict__ as2,
                                                   const float* __restrict__ ad2,
                                                   float* __restrict__ vs,
                                                   float* __restrict__ vd) {
    int slot = blockIdx.x;
    const float* W  = (slot < 4) ? W1 : (slot < 8) ? Wr : W2;
    const float* s_ = (slot < 4) ? as1 : (slot < 8) ? asr : as2;
    const float* d_ = (slot < 4) ? ad1 : (slot < 8) ? adr : ad2;
    int h = slot & 3;
    int wave = threadIdx.x >> 6, lane = threadIdx.x & 63;
    int rbase = blockIdx.y * 32 + wave * 8;
    float as0 = s_[h * C + lane], as1v = s_[h * C + 64 + lane];
    float ad0 = d_[h * C + lane], ad1v = d_[h * C + 64 + lane];
    #pragma unroll
    for (int j = 0; j < 8; ++j) {
        int i = rbase + j;
        const float* Wrow = W + ((size_t)h * C + i) * C;
        float w0 = Wrow[lane], w1 = Wrow[64 + lane];
        float ps = w0 * as0 + w1 * as1v;
        float pd = w0 * ad0 + w1 * ad1v;
        #pragma unroll
        for (int m = 32; m; m >>= 1) {
            ps += __shfl_xor(ps, m);
            pd += __shfl_xor(pd, m);
        }
        if (lane == 0) { vs[slot * C + i] = ps; vd[slot * C + i] = pd; }
    }
}

// ---------------- fused cvt_x + 8-slot logits (layer1 + residual) ----------------

__global__ __launch_bounds__(256) void al8f_kernel(const float* __restrict__ x,
                                                   const float* __restrict__ vs,
                                                   const float* __restrict__ vd,
                                                   u16* __restrict__ xb,
                                                   float* __restrict__ als,
                                                   float* __restrict__ ald, int N) {
    int node = blockIdx.x * 4 + (threadIdx.x >> 6);
    int lane = threadIdx.x & 63;
    if (node >= N) return;
    float x0 = x[(size_t)node * C + lane];
    float x1 = x[(size_t)node * C + 64 + lane];
    xb[(size_t)node * C + lane] = f2b(x0);
    xb[(size_t)node * C + 64 + lane] = f2b(x1);
    #pragma unroll
    for (int h = 0; h < 8; ++h) {
        float ps = x0 * vs[h * C + lane] + x1 * vs[h * C + 64 + lane];
        float pd = x0 * vd[h * C + lane] + x1 * vd[h * C + 64 + lane];
        #pragma unroll
        for (int m = 32; m; m >>= 1) {
            ps += __shfl_xor(ps, m);
            pd += __shfl_xor(pd, m);
        }
        if (lane == 0) { als[node * 8 + h] = ps; ald[node * 8 + h] = pd; }
    }
}

// ---------------- layer-2 logits from bf16 h1 ----------------

__global__ __launch_bounds__(256) void al4_kernel(const u16* __restrict__ in,
                                                  const float* __restrict__ vs,
                                                  const float* __restrict__ vd,
                                                  float* __restrict__ als,
                                                  float* __restrict__ ald, int N) {
    int node = blockIdx.x * 4 + (threadIdx.x >> 6);
    int lane = threadIdx.x & 63;
    if (node >= N) return;
    float x0 = b2f(in[(size_t)node * C + lane]);
    float x1 = b2f(in[(size_t)node * C + 64 + lane]);
    #pragma unroll
    for (int h = 0; h < 4; ++h) {
        float ps = x0 * vs[h * C + lane] + x1 * vs[h * C + 64 + lane];
        float pd = x0 * vd[h * C + lane] + x1 * vd[h * C + 64 + lane];
        #pragma unroll
        for (int m = 32; m; m >>= 1) {
            ps += __shfl_xor(ps, m);
            pd += __shfl_xor(pd, m);
        }
        if (lane == 0) { als[node * 4 + h] = ps; ald[node * 4 + h] = pd; }
    }
}

// ---------------- edge-parallel unnormalized weights: w[i][h] ----------------

template <int NH>
__global__ __launch_bounds__(256) void ew_kernel(const float* __restrict__ als,
                                                 const float* __restrict__ ald,
                                                 const int* __restrict__ srcs,
                                                 const int* __restrict__ dsts,
                                                 float* __restrict__ wout, int ET) {
    int i = blockIdx.x * blockDim.x + threadIdx.x;
    if (i >= ET) return;
    int s = srcs[i], d = dsts[i];
    const float* as_ = als + (size_t)s * NH;
    const float* ad_ = ald + (size_t)d * NH;
    float* wo = wout + (size_t)i * NH;
    #pragma unroll
    for (int h = 0; h < NH; ++h) {
        wo[h] = __expf(lrelu(as_[h] + ad_[h]));
    }
}

// ---------------- aggregation: dest[n][h*128+c] = inv[h]*sum_e w[e,h]*xsrc[c] --------
// 2 waves per node (half = wave&1), combined via LDS; lane owns 2 channels, all heads.

template <int NH>
__global__ __launch_bounds__(256) void aggx_kernel(const u16* __restrict__ xsrc,
                                                   const float* __restrict__ wgt,
                                                   const int* __restrict__ offs,
                                                   const int* __restrict__ srcs,
                                                   u16* __restrict__ dest, int N) {
    int wave = threadIdx.x >> 6, lane = threadIdx.x & 63;
    int nl = wave >> 1, half = wave & 1;
    int node = blockIdx.x * 2 + nl;
    bool valid = node < N;
    int beg = valid ? offs[node] : 0;
    int end = valid ? offs[node + 1] : 0;
    int c0 = lane * 2;

    // phase 1 (half 0 only): denominators from contiguous wgt
    float invh[NH];
    if (half == 0) {
        int h1 = lane & (NH - 1);
        int io = lane / NH;
        constexpr int EP = 64 / NH;
        float dn = 0.f;
        for (int i = beg + io; i < end; i += EP) {
            dn += wgt[(size_t)i * NH + h1];
        }
        #pragma unroll
        for (int m = NH; m < 64; m <<= 1) dn += __shfl_xor(dn, m);
        #pragma unroll
        for (int h = 0; h < NH; ++h) invh[h] = 1.f / __shfl(dn, h);
    }

    // phase 2: this wave's interleaved 4-edge chunks
    float acc[NH][2];
    #pragma unroll
    for (int h = 0; h < NH; ++h) { acc[h][0] = 0.f; acc[h][1] = 0.f; }

    for (int i0 = beg + half * 4; i0 < end; i0 += 8) {
        int cnt = end - i0; if (cnt > 4) cnt = 4;
        if (cnt == 4) {
            int s0 = srcs[i0], s1 = srcs[i0 + 1], s2 = srcs[i0 + 2], s3 = srcs[i0 + 3];
            float w[4][NH];
            #pragma unroll
            for (int e = 0; e < 4; ++e) {
                const float4* wp = (const float4*)(wgt + (size_t)(i0 + e) * NH);
                float4 wa = wp[0];
                w[e][0] = wa.x; w[e][1] = wa.y; w[e][2] = wa.z; w[e][3] = wa.w;
                if constexpr (NH == 8) {
                    float4 wb = wp[1];
                    w[e][4] = wb.x; w[e][5] = wb.y; w[e][6] = wb.z; w[e][7] = wb.w;
                }
            }
            unsigned v0 = *(const unsigned*)(xsrc + (size_t)s0 * C + c0);
            unsigned v1 = *(const unsigned*)(xsrc + (size_t)s1 * C + c0);
            unsigned v2 = *(const unsigned*)(xsrc + (size_t)s2 * C + c0);
            unsigned v3 = *(const unsigned*)(xsrc + (size_t)s3 * C + c0);
            float f00 = b2f((u16)(v0 & 0xffff)), f01 = b2f((u16)(v0 >> 16));
            float f10 = b2f((u16)(v1 & 0xffff)), f11 = b2f((u16)(v1 >> 16));
            float f20 = b2f((u16)(v2 & 0xffff)), f21 = b2f((u16)(v2 >> 16));
            float f30 = b2f((u16)(v3 & 0xffff)), f31 = b2f((u16)(v3 >> 16));
            #pragma unroll
            for (int h = 0; h < NH; ++h) {
                acc[h][0] += w[0][h] * f00 + w[1][h] * f10 + w[2][h] * f20 + w[3][h] * f30;
                acc[h][1] += w[0][h] * f01 + w[1][h] * f11 + w[2][h] * f21 + w[3][h] * f31;
            }
        } else {
            for (int e = 0; e < cnt; ++e) {
                int s0 = srcs[i0 + e];
                const float4* wp = (const float4*)(wgt + (size_t)(i0 + e) * NH);
                float4 wa = wp[0];
                float w0[NH];
                w0[0] = wa.x; w0[1] = wa.y; w0[2] = wa.z; w0[3] = wa.w;
                if constexpr (NH == 8) {
                    float4 wb = wp[1];
                    w0[4] = wb.x; w0[5] = wb.y; w0[6] = wb.z; w0[7] = wb.w;
                }
                unsigned v0 = *(const unsigned*)(xsrc + (size_t)s0 * C + c0);
                float f0 = b2f((u16)(v0 & 0xffff)), f1 = b2f((u16)(v0 >> 16));
                #pragma unroll
                for (int h = 0; h < NH; ++h) {
                    acc[h][0] += w0[h] * f0;
                    acc[h][1] += w0[h] * f1;
                }
            }
        }
    }

    // combine halves via LDS (lane-contiguous layout: 2-way bank alias only)
    __shared__ float s_acc[2][NH * 2][64];
    if (half == 1) {
        #pragma unroll
        for (int h = 0; h < NH; ++h) {
            s_acc[nl][h * 2 + 0][lane] = acc[h][0];
            s_acc[nl][h * 2 + 1][lane] = acc[h][1];
        }
    }
    __syncthreads();
    if (half == 0 && valid) {
        #pragma unroll
        for (int h = 0; h < NH; ++h) {
            float r0 = (acc[h][0] + s_acc[nl][h * 2 + 0][lane]) * invh[h];
            float r1 = (acc[h][1] + s_acc[nl][h * 2 + 1][lane]) * invh[h];
            u16x2 o = {f2b(r0), f2b(r1)};
            *(u16x2*)(dest + (size_t)node * (NH * C) + h * C + c0) = o;
        }
    }
}

// ---------------- post-GEMM: out[n][128] = A[n][512] @ Wc^T (+bias), full width ------
// MODE 0: write bf16; 1: write f32; 2: accumulate f32.

template <int MODE>
__global__ __launch_bounds__(256) void gemm2_kernel(const u16* __restrict__ A, int lda,
                                                    const u16* __restrict__ Wc,
                                                    const float* __restrict__ bias,
                                                    u16* __restrict__ outb,
                                                    float* __restrict__ outf, int N) {
    int wave = threadIdx.x >> 6, lane = threadIdx.x & 63;
    int rowBase = blockIdx.x * 64 + wave * 16;
    int r = rowBase + (lane & 15);
    int rl = r < N ? r : N - 1;
    int kg = (lane >> 4) * 8;

    const short8* ap = (const short8*)(A + (size_t)rl * lda + kg);
    short8 a[16];
    #pragma unroll
    for (int kk = 0; kk < 16; ++kk) a[kk] = ap[kk * 4];

    f32x4 acc[8];
    #pragma unroll
    for (int t = 0; t < 8; ++t) acc[t] = (f32x4){0.f, 0.f, 0.f, 0.f};

    #pragma unroll
    for (int t = 0; t < 8; ++t) {
        int col = t * 16 + (lane & 15);
        const short8* bp = (const short8*)(Wc + (size_t)col * 512 + kg);
        #pragma unroll
        for (int kk = 0; kk < 16; ++kk) {
            acc[t] = __builtin_amdgcn_mfma_f32_16x16x32_bf16(a[kk], bp[kk * 4], acc[t], 0, 0, 0);
        }
    }

    int prow = rowBase + (lane >> 4) * 4;
    #pragma unroll
    for (int t = 0; t < 8; ++t) {
        int col = t * 16 + (lane & 15);
        float bcol = bias[col];
        #pragma unroll
        for (int j = 0; j < 4; ++j) {
            int rr = prow + j;
            if (rr < N) {
                float v = acc[t][j] + bcol;
                if (MODE == 0) outb[(size_t)rr * C + col] = f2b(v);
                else if (MODE == 1) outf[(size_t)rr * C + col] = v;
                else outf[(size_t)rr * C + col] += v;
            }
        }
    }
}

// ---------------- launch ----------------

extern "C" void kernel_launch(void* const* d_in, const int* in_sizes, int n_in,
                              void* d_out, int out_size, void* d_ws, size_t ws_size,
                              hipStream_t stream) {
    const float* x = (const float*)d_in[0];
    const int* ei = (const int*)d_in[1];
    const float* W1 = (const float*)d_in[2];
    const float* as1 = (const float*)d_in[3];
    const float* ad1 = (const float*)d_in[4];
    const float* b1 = (const float*)d_in[5];
    const float* W2 = (const float*)d_in[6];
    const float* as2 = (const float*)d_in[7];
    const float* ad2 = (const float*)d_in[8];
    const float* b2 = (const float*)d_in[9];
    const float* Wr = (const float*)d_in[10];
    const float* asr = (const float*)d_in[11];
    const float* adr = (const float*)d_in[12];
    const float* br = (const float*)d_in[13];

    int N = in_sizes[0] / C;   // 20000
    int E = in_sizes[1] / 2;   // 320000
    int ET = E + N;

    size_t sz_xb    = (size_t)N * C * 2;
    size_t sz_h1b   = (size_t)N * C * 2;
    size_t sz_aggA  = (size_t)N * 1024 * 2;   // heads 0-3: layer1; 4-7: residual
    size_t sz_aggB  = (size_t)N * 512 * 2;
    size_t sz_wc    = (size_t)3 * C * 512 * 2;
    size_t sz_v     = (size_t)12 * C * 4;
    size_t sz_al8   = (size_t)N * 8 * 4;
    size_t sz_count = (size_t)N * 4;
    size_t sz_offs  = (size_t)(N + 4) * 4;
    size_t sz_srcs  = (size_t)ET * 4;
    size_t sz_w     = (size_t)ET * 8 * 4;     // reused for NH=4
    size_t required = sz_xb + sz_h1b + sz_aggA + sz_aggB + sz_wc + 2 * sz_v +
                      2 * sz_al8 + 2 * sz_count + sz_offs + 2 * sz_srcs + sz_w;
    if (ws_size < required) return;

    char* w = (char*)d_ws;
    u16* xb = (u16*)w;        w += sz_xb;
    u16* h1b = (u16*)w;       w += sz_h1b;
    u16* aggA = (u16*)w;      w += sz_aggA;
    u16* aggB = (u16*)w;      w += sz_aggB;
    u16* Wc = (u16*)w;        w += sz_wc;
    float* vs = (float*)w;    w += sz_v;
    float* vd = (float*)w;    w += sz_v;
    float* als = (float*)w;   w += sz_al8;
    float* ald = (float*)w;   w += sz_al8;
    int* count = (int*)w;     w += sz_count;
    int* cursor = (int*)w;    w += sz_count;
    int* offs = (int*)w;      w += sz_offs;
    int* srcs = (int*)w;      w += sz_srcs;
    int* dsts = (int*)w;      w += sz_srcs;
    float* wgt = (float*)w;   w += sz_w;
    float* out = (float*)d_out;

    const u16* Wc1 = Wc;
    const u16* Wcr = Wc + (size_t)C * 512;
    const u16* Wc2 = Wc + (size_t)2 * C * 512;

    hipMemsetAsync(count, 0, sz_count, stream);
    hist_kernel<<<512, 256, 0, stream>>>(ei, E, N, count);
    scan_kernel<<<1, 1024, 0, stream>>>(count, offs, cursor, N);
    scatter_kernel<<<512, 256, 0, stream>>>(ei, E, N, cursor, srcs, dsts);

    cvt_w_kernel<<<384, 128, 0, stream>>>(W1, Wr, W2, Wc);
    wvec_kernel<<<dim3(12, 4), 256, 0, stream>>>(W1, as1, ad1, Wr, asr, adr,
                                                 W2, as2, ad2, vs, vd);

    int nwb = (N + 3) / 4;
    int npb = (N + 1) / 2;
    int neb = (ET + 255) / 256;
    int gx = (N + 63) / 64;

    // group A: layer1 + residual (share the x gather)
    al8f_kernel<<<nwb, 256, 0, stream>>>(x, vs, vd, xb, als, ald, N);
    ew_kernel<8><<<neb, 256, 0, stream>>>(als, ald, srcs, dsts, wgt, ET);
    aggx_kernel<8><<<npb, 256, 0, stream>>>(xb, wgt, offs, srcs, aggA, N);
    gemm2_kernel<0><<<gx, 256, 0, stream>>>(aggA, 1024, Wc1, b1, h1b, out, N);
    gemm2_kernel<1><<<gx, 256, 0, stream>>>(aggA + 512, 1024, Wcr, br, h1b, out, N);

    // group B: layer2
    al4_kernel<<<nwb, 256, 0, stream>>>(h1b, vs + 8 * C, vd + 8 * C, als, ald, N);
    ew_kernel<4><<<neb, 256, 0, stream>>>(als, ald, srcs, dsts, wgt, ET);
    aggx_kernel<4><<<npb, 256, 0, stream>>>(h1b, wgt, offs, srcs, aggB, N);
    gemm2_kernel<2><<<gx, 256, 0, stream>>>(aggB, 512, Wc2, b2, h1b, out, N);
}